// Round 2
// baseline (614.667 us; speedup 1.0000x reference)
//
#include <hip/hip_runtime.h>
#include <math.h>

// Problem constants
#define NROWS 65536
#define DDIM  1024
#define NEXP  64
#define BM    32      // rows per block (small tile -> 8 independent blocks/CU)
#define BK    32      // K chunk (== one MFMA K)
#define NK    (DDIM / BK)
#define LDX   40      // split-plane leading dim in bf16 elements (80 B rows)
#define PLANE (BM * LDX)          // 1280 shorts per split plane
#define WCHUNK 12288  // shorts per k32-chunk of packed w: 3 splits * 128 n * 32 k

typedef short bf16x8 __attribute__((ext_vector_type(8)));
typedef float f32x4  __attribute__((ext_vector_type(4)));

// exact-ish 3-way bf16 split, round-to-nearest (used in one-time w prep)
__device__ __forceinline__ void split3(float x, unsigned short& h,
                                       unsigned short& m, unsigned short& l) {
    unsigned u = __float_as_uint(x);
    unsigned r = u + 0x7FFFu + ((u >> 16) & 1u);
    h = (unsigned short)(r >> 16);
    float hf = __uint_as_float(r & 0xFFFF0000u);
    float r1 = x - hf;
    unsigned u2 = __float_as_uint(r1);
    unsigned r2 = u2 + 0x7FFFu + ((u2 >> 16) & 1u);
    m = (unsigned short)(r2 >> 16);
    float mf = __uint_as_float(r2 & 0xFFFF0000u);
    float r3 = r1 - mf;
    unsigned u3 = __float_as_uint(r3);
    unsigned r4 = u3 + 0x7FFFu + ((u3 >> 16) & 1u);
    l = (unsigned short)(r4 >> 16);
}

// cheap truncation split for the hot x path: x = h + m + l + O(2^-24 x)
__device__ __forceinline__ void split3t(float x, unsigned& h, unsigned& m, unsigned& l) {
    unsigned u = __float_as_uint(x);
    h = u >> 16;
    float r1 = x - __uint_as_float(u & 0xFFFF0000u);
    unsigned u2 = __float_as_uint(r1);
    m = u2 >> 16;
    float r2 = r1 - __uint_as_float(u2 & 0xFFFF0000u);
    l = __float_as_uint(r2) >> 16;
}

__device__ __forceinline__ float softplus_f(float x) {
    return fmaxf(x, 0.0f) + log1pf(expf(-fabsf(x)));
}

// Pack weights: wp[chunk][split][n][32] bf16, n = 0..63 route, 64..127 noise.
__global__ void __launch_bounds__(256) prep_w_kernel(
        const float* __restrict__ wr, const float* __restrict__ wn,
        short* __restrict__ wp) {
    int idx = blockIdx.x * 256 + threadIdx.x;   // 0..131071
    int n = idx >> 10;
    int k = idx & 1023;
    float v = (n < NEXP) ? wr[n * DDIM + k] : wn[(n - NEXP) * DDIM + k];
    unsigned short h, m, l;
    split3(v, h, m, l);
    int base = (k >> 5) * WCHUNK + n * 32 + (k & 31);
    wp[base]        = (short)h;
    wp[base + 4096] = (short)m;
    wp[base + 8192] = (short)l;
}

__device__ __forceinline__ void stage_split(float4 v, short* plane, int row, int kq) {
    const float* vp = (const float*)&v;
    unsigned hs[3][4];
#pragma unroll
    for (int j = 0; j < 4; ++j) split3t(vp[j], hs[0][j], hs[1][j], hs[2][j]);
#pragma unroll
    for (int s = 0; s < 3; ++s) {
        uint2 p;
        p.x = (hs[s][0] & 0xFFFFu) | (hs[s][1] << 16);
        p.y = (hs[s][2] & 0xFFFFu) | (hs[s][3] << 16);
        *(uint2*)(plane + s * PLANE + row * LDX + kq) = p;
    }
}

__device__ __forceinline__ void top2_merge(float& v0, int& i0, float& v1, int& i1,
                                           float pv0, int pi0, float pv1, int pi1) {
    bool t0 = (pv0 > v0) || (pv0 == v0 && pi0 < i0);
    if (t0) {
        bool t1 = (v0 > pv1) || (v0 == pv1 && i0 < pi1);
        v1 = t1 ? v0 : pv1; i1 = t1 ? i0 : pi1;
        v0 = pv0; i0 = pi0;
    } else {
        bool t1 = (pv0 > v1) || (pv0 == v1 && pi0 < i1);
        if (t1) { v1 = pv0; i1 = pi0; }
    }
}

__global__ void __launch_bounds__(256, 8) router_kernel(
        const float* __restrict__ x, const short* __restrict__ wp,
        const float* __restrict__ eps, float* __restrict__ out) {
    // Double-buffered split planes: 2 bufs x 3 splits x [32][40] bf16 = 15360 B.
    // Epilogue reuses the same region as noisy[32][66] fp32 = 8448 B.
    __shared__ __align__(16) char smem[2 * 3 * PLANE * 2];
    __shared__ float4 rowout[BM];
    short* xs = (short*)smem;

    const int tid    = threadIdx.x;
    const int lane   = tid & 63;
    const int wv     = tid >> 6;      // wave 0..3 -> col group
    const int lane16 = lane & 15;
    const int quad   = lane >> 4;
    const int blockM = blockIdx.x * BM;

    // staging coords: thread covers one float4 at (srow, skq)
    const int srow = tid >> 3;            // 0..31
    const int skq  = (tid & 7) << 2;      // 0,4,..28
    const float* xp = x + (size_t)(blockM + srow) * DDIM + skq;

    // wave's expert columns: route col_r, noise col_r+64 in packed w
    const int col_r = wv * 16 + lane16;

    f32x4 acc[2][2];   // [mi][0]=route, [1]=noise
#pragma unroll
    for (int a = 0; a < 2; ++a) { acc[a][0] = (f32x4)0.0f; acc[a][1] = (f32x4)0.0f; }

    float4 xv = *(const float4*)xp;

#pragma unroll 2
    for (int kc = 0; kc < NK; ++kc) {
        short* plane = xs + (kc & 1) * 3 * PLANE;
        const short* wpc = wp + (size_t)kc * WCHUNK;

        // B fragments for this kc (L1/L2-hot; issued before split phase)
        bf16x8 Bf[3][2];
#pragma unroll
        for (int s = 0; s < 3; ++s) {
            Bf[s][0] = *(const bf16x8*)(wpc + s * 4096 + col_r * 32 + quad * 8);
            Bf[s][1] = *(const bf16x8*)(wpc + s * 4096 + (col_r + 64) * 32 + quad * 8);
        }

        // split current x chunk into 3 bf16 planes (once per element per block)
        stage_split(xv, plane, srow, skq);
        __syncthreads();

        // prefetch next chunk's x (hidden behind the MFMA block below)
        if (kc < NK - 1) xv = *(const float4*)(xp + (kc + 1) * BK);

#pragma unroll
        for (int mi = 0; mi < 2; ++mi) {
            bf16x8 Af[3];
#pragma unroll
            for (int s = 0; s < 3; ++s)
                Af[s] = *(const bf16x8*)(plane + s * PLANE +
                          (mi * 16 + lane16) * LDX + quad * 8);
            __builtin_amdgcn_s_setprio(1);
#pragma unroll
            for (int ni = 0; ni < 2; ++ni) {
                f32x4 c = acc[mi][ni];
                // small-terms-first accumulation: lh, hl, mm, mh, hm, hh
                c = __builtin_amdgcn_mfma_f32_16x16x32_bf16(Af[2], Bf[0][ni], c, 0, 0, 0);
                c = __builtin_amdgcn_mfma_f32_16x16x32_bf16(Af[0], Bf[2][ni], c, 0, 0, 0);
                c = __builtin_amdgcn_mfma_f32_16x16x32_bf16(Af[1], Bf[1][ni], c, 0, 0, 0);
                c = __builtin_amdgcn_mfma_f32_16x16x32_bf16(Af[1], Bf[0][ni], c, 0, 0, 0);
                c = __builtin_amdgcn_mfma_f32_16x16x32_bf16(Af[0], Bf[1][ni], c, 0, 0, 0);
                c = __builtin_amdgcn_mfma_f32_16x16x32_bf16(Af[0], Bf[0][ni], c, 0, 0, 0);
                acc[mi][ni] = c;
            }
            __builtin_amdgcn_s_setprio(0);
        }
        // no second barrier: next iteration's writes go to the other buffer, and
        // the pre-barrier lgkmcnt(0) drain at kc+1 protects buf reuse at kc+2.
    }
    __syncthreads();   // protect smem reuse (noisy overlaps plane buffers)

    // ---------------- Epilogue ----------------
    // C-frag: row = quad*4 + v, col = lane16  [verified]
    float* noisy = (float*)smem;   // [32][66]
#pragma unroll
    for (int mi = 0; mi < 2; ++mi)
#pragma unroll
        for (int v = 0; v < 4; ++v) {
            int row = mi * 16 + quad * 4 + v;
            float ev = eps[(size_t)(blockM + row) * NEXP + col_r];
            noisy[row * 66 + col_r] =
                fmaf(ev, softplus_f(acc[mi][1][v]), acc[mi][0][v]);
        }
    __syncthreads();

    // top-2: 8 threads/row scan 8 cols each, merge via shfl_xor(1,2,4)
    {
        int row = tid >> 3;
        int sub = tid & 7;
        float v0 = -INFINITY, v1 = -INFINITY;
        int   i0 = 1 << 20,   i1 = 1 << 20;
#pragma unroll
        for (int j = 0; j < 8; ++j) {
            int col = sub * 8 + j;
            float v = noisy[row * 66 + col];
            if (v > v0) { v1 = v0; i1 = i0; v0 = v; i0 = col; }
            else if (v > v1) { v1 = v; i1 = col; }
        }
#pragma unroll
        for (int d = 1; d <= 4; d <<= 1) {
            float pv0 = __shfl_xor(v0, d, 64);
            int   pi0 = __shfl_xor(i0, d, 64);
            float pv1 = __shfl_xor(v1, d, 64);
            int   pi1 = __shfl_xor(i1, d, 64);
            top2_merge(v0, i0, v1, i1, pv0, pi0, pv1, pi1);
        }
        if (sub == 0) {
            float e1  = expf(v1 - v0);
            float inv = 1.0f / (1.0f + e1);
            rowout[row] = make_float4(inv, e1 * inv,
                                      __int_as_float(i0), __int_as_float(i1));
            float* idx_out = out + (size_t)NROWS * NEXP;
            *(float2*)&idx_out[(size_t)(blockM + row) * 2] =
                make_float2((float)i0, (float)i1);
        }
    }
    __syncthreads();

    // coalesced [32][64] output tile write
#pragma unroll
    for (int it = 0; it < 2; ++it) {
        int f  = it * 256 + tid;       // float4 id 0..511
        int m  = f >> 4;
        int c4 = (f & 15) << 2;
        float4 ro = rowout[m];
        int i0 = __float_as_int(ro.z);
        int i1 = __float_as_int(ro.w);
        float4 o;
        float* op = (float*)&o;
#pragma unroll
        for (int j = 0; j < 4; ++j) {
            int col = c4 + j;
            op[j] = (col == i0) ? ro.x : (col == i1) ? ro.y : 0.0f;
        }
        *(float4*)&out[(size_t)(blockM + m) * NEXP + c4] = o;
    }
}

extern "C" void kernel_launch(void* const* d_in, const int* in_sizes, int n_in,
                              void* d_out, int out_size, void* d_ws, size_t ws_size,
                              hipStream_t stream) {
    const float* x   = (const float*)d_in[0];
    const float* wr  = (const float*)d_in[1];
    const float* wn  = (const float*)d_in[2];
    const float* eps = (const float*)d_in[3];
    float* out = (float*)d_out;
    short* wp  = (short*)d_ws;   // 32 chunks * 12288 shorts = 1.5 MB scratch

    prep_w_kernel<<<dim3(512), dim3(256), 0, stream>>>(wr, wn, wp);
    router_kernel<<<dim3(NROWS / BM), dim3(256), 0, stream>>>(x, wp, eps, out);
}

// Round 3
// 448.324 us; speedup vs baseline: 1.3710x; 1.3710x over previous
//
#include <hip/hip_runtime.h>
#include <math.h>

// Problem constants
#define NROWS 65536
#define DDIM  1024
#define NEXP  64
#define BM    32      // rows per block (small tile -> 8 independent blocks/CU)
#define BK    32      // K chunk (== one MFMA K)
#define NK    (DDIM / BK)
#define LDX   40      // split-plane leading dim in bf16 elements (80 B rows)
#define PLANE (BM * LDX)          // 1280 shorts per split plane
#define WCHUNK 12288  // shorts per k32-chunk of packed w: 3 splits * 128 n * 32 k

typedef short bf16x8 __attribute__((ext_vector_type(8)));
typedef float f32x4  __attribute__((ext_vector_type(4)));

// exact-ish 3-way bf16 split, round-to-nearest (used in one-time w prep)
__device__ __forceinline__ void split3(float x, unsigned short& h,
                                       unsigned short& m, unsigned short& l) {
    unsigned u = __float_as_uint(x);
    unsigned r = u + 0x7FFFu + ((u >> 16) & 1u);
    h = (unsigned short)(r >> 16);
    float hf = __uint_as_float(r & 0xFFFF0000u);
    float r1 = x - hf;
    unsigned u2 = __float_as_uint(r1);
    unsigned r2 = u2 + 0x7FFFu + ((u2 >> 16) & 1u);
    m = (unsigned short)(r2 >> 16);
    float mf = __uint_as_float(r2 & 0xFFFF0000u);
    float r3 = r1 - mf;
    unsigned u3 = __float_as_uint(r3);
    unsigned r4 = u3 + 0x7FFFu + ((u3 >> 16) & 1u);
    l = (unsigned short)(r4 >> 16);
}

// cheap truncation split for the hot x path: x = h + m + l + O(2^-24 x)
__device__ __forceinline__ void split3t(float x, unsigned& h, unsigned& m, unsigned& l) {
    unsigned u = __float_as_uint(x);
    h = u >> 16;
    float r1 = x - __uint_as_float(u & 0xFFFF0000u);
    unsigned u2 = __float_as_uint(r1);
    m = u2 >> 16;
    float r2 = r1 - __uint_as_float(u2 & 0xFFFF0000u);
    l = __float_as_uint(r2) >> 16;
}

__device__ __forceinline__ float softplus_f(float x) {
    return fmaxf(x, 0.0f) + log1pf(expf(-fabsf(x)));
}

// Pack weights: wp[chunk][split][n][32] bf16, n = 0..63 route, 64..127 noise.
__global__ void __launch_bounds__(256) prep_w_kernel(
        const float* __restrict__ wr, const float* __restrict__ wn,
        short* __restrict__ wp) {
    int idx = blockIdx.x * 256 + threadIdx.x;   // 0..131071
    int n = idx >> 10;
    int k = idx & 1023;
    float v = (n < NEXP) ? wr[n * DDIM + k] : wn[(n - NEXP) * DDIM + k];
    unsigned short h, m, l;
    split3(v, h, m, l);
    int base = (k >> 5) * WCHUNK + n * 32 + (k & 31);
    wp[base]        = (short)h;
    wp[base + 4096] = (short)m;
    wp[base + 8192] = (short)l;
}

__device__ __forceinline__ void stage_split(float4 v, short* plane, int row, int kq) {
    const float* vp = (const float*)&v;
    unsigned hs[3][4];
#pragma unroll
    for (int j = 0; j < 4; ++j) split3t(vp[j], hs[0][j], hs[1][j], hs[2][j]);
#pragma unroll
    for (int s = 0; s < 3; ++s) {
        uint2 p;
        p.x = (hs[s][0] & 0xFFFFu) | (hs[s][1] << 16);
        p.y = (hs[s][2] & 0xFFFFu) | (hs[s][3] << 16);
        *(uint2*)(plane + s * PLANE + row * LDX + kq) = p;
    }
}

__device__ __forceinline__ void top2_merge(float& v0, int& i0, float& v1, int& i1,
                                           float pv0, int pi0, float pv1, int pi1) {
    bool t0 = (pv0 > v0) || (pv0 == v0 && pi0 < i0);
    if (t0) {
        bool t1 = (v0 > pv1) || (v0 == pv1 && i0 < pi1);
        v1 = t1 ? v0 : pv1; i1 = t1 ? i0 : pi1;
        v0 = pv0; i0 = pi0;
    } else {
        bool t1 = (pv0 > v1) || (pv0 == v1 && pi0 < i1);
        if (t1) { v1 = pv0; i1 = pi0; }
    }
}

// launch_bounds(256, 4): 4 waves/EU floor for regalloc (~128 VGPR budget) so the
// ~60-reg live set NEVER spills (round-2 lesson: (256,8) -> 32 VGPRs -> 403 MB
// scratch traffic). Achieved occupancy is grid/LDS/VGPR-limited, not capped by
// this hint: expected allocator result ~48-56 VGPR -> 8 blocks/CU reachable.
__global__ void __launch_bounds__(256, 4) router_kernel(
        const float* __restrict__ x, const short* __restrict__ wp,
        const float* __restrict__ eps, float* __restrict__ out) {
    // Double-buffered split planes: 2 bufs x 3 splits x [32][40] bf16 = 15360 B.
    // Epilogue reuses the same region as noisy[32][66] fp32 = 8448 B.
    __shared__ __align__(16) char smem[2 * 3 * PLANE * 2];
    __shared__ float4 rowout[BM];
    short* xs = (short*)smem;

    const int tid    = threadIdx.x;
    const int lane   = tid & 63;
    const int wv     = tid >> 6;      // wave 0..3 -> col group
    const int lane16 = lane & 15;
    const int quad   = lane >> 4;
    const int blockM = blockIdx.x * BM;

    // staging coords: thread covers one float4 at (srow, skq)
    const int srow = tid >> 3;            // 0..31
    const int skq  = (tid & 7) << 2;      // 0,4,..28
    const float* xp = x + (size_t)(blockM + srow) * DDIM + skq;

    // wave's expert columns: route col_r, noise col_r+64 in packed w
    const int col_r = wv * 16 + lane16;

    f32x4 acc[2][2];   // [mi][0]=route, [1]=noise
#pragma unroll
    for (int a = 0; a < 2; ++a) { acc[a][0] = (f32x4)0.0f; acc[a][1] = (f32x4)0.0f; }

    float4 xv = *(const float4*)xp;

#pragma unroll 2
    for (int kc = 0; kc < NK; ++kc) {
        short* plane = xs + (kc & 1) * 3 * PLANE;
        const short* wpc = wp + (size_t)kc * WCHUNK;

        // B fragments for this kc (L1/L2-hot; issued before split phase)
        bf16x8 Bf[3][2];
#pragma unroll
        for (int s = 0; s < 3; ++s) {
            Bf[s][0] = *(const bf16x8*)(wpc + s * 4096 + col_r * 32 + quad * 8);
            Bf[s][1] = *(const bf16x8*)(wpc + s * 4096 + (col_r + 64) * 32 + quad * 8);
        }

        // split current x chunk into 3 bf16 planes (once per element per block)
        stage_split(xv, plane, srow, skq);
        __syncthreads();

        // prefetch next chunk's x (hidden behind the MFMA block below)
        if (kc < NK - 1) xv = *(const float4*)(xp + (kc + 1) * BK);

#pragma unroll
        for (int mi = 0; mi < 2; ++mi) {
            bf16x8 Af[3];
#pragma unroll
            for (int s = 0; s < 3; ++s)
                Af[s] = *(const bf16x8*)(plane + s * PLANE +
                          (mi * 16 + lane16) * LDX + quad * 8);
            __builtin_amdgcn_s_setprio(1);
#pragma unroll
            for (int ni = 0; ni < 2; ++ni) {
                f32x4 c = acc[mi][ni];
                // small-terms-first accumulation: lh, hl, mm, mh, hm, hh
                c = __builtin_amdgcn_mfma_f32_16x16x32_bf16(Af[2], Bf[0][ni], c, 0, 0, 0);
                c = __builtin_amdgcn_mfma_f32_16x16x32_bf16(Af[0], Bf[2][ni], c, 0, 0, 0);
                c = __builtin_amdgcn_mfma_f32_16x16x32_bf16(Af[1], Bf[1][ni], c, 0, 0, 0);
                c = __builtin_amdgcn_mfma_f32_16x16x32_bf16(Af[1], Bf[0][ni], c, 0, 0, 0);
                c = __builtin_amdgcn_mfma_f32_16x16x32_bf16(Af[0], Bf[1][ni], c, 0, 0, 0);
                c = __builtin_amdgcn_mfma_f32_16x16x32_bf16(Af[0], Bf[0][ni], c, 0, 0, 0);
                acc[mi][ni] = c;
            }
            __builtin_amdgcn_s_setprio(0);
        }
        // no second barrier: next iteration's writes go to the other buffer, and
        // the pre-barrier drain at kc+1 protects buf reuse at kc+2.
    }
    __syncthreads();   // protect smem reuse (noisy overlaps plane buffers)

    // ---------------- Epilogue ----------------
    // C-frag: row = quad*4 + v, col = lane16  [verified]
    float* noisy = (float*)smem;   // [32][66]
#pragma unroll
    for (int mi = 0; mi < 2; ++mi)
#pragma unroll
        for (int v = 0; v < 4; ++v) {
            int row = mi * 16 + quad * 4 + v;
            float ev = eps[(size_t)(blockM + row) * NEXP + col_r];
            noisy[row * 66 + col_r] =
                fmaf(ev, softplus_f(acc[mi][1][v]), acc[mi][0][v]);
        }
    __syncthreads();

    // top-2: 8 threads/row scan 8 cols each, merge via shfl_xor(1,2,4)
    {
        int row = tid >> 3;
        int sub = tid & 7;
        float v0 = -INFINITY, v1 = -INFINITY;
        int   i0 = 1 << 20,   i1 = 1 << 20;
#pragma unroll
        for (int j = 0; j < 8; ++j) {
            int col = sub * 8 + j;
            float v = noisy[row * 66 + col];
            if (v > v0) { v1 = v0; i1 = i0; v0 = v; i0 = col; }
            else if (v > v1) { v1 = v; i1 = col; }
        }
#pragma unroll
        for (int d = 1; d <= 4; d <<= 1) {
            float pv0 = __shfl_xor(v0, d, 64);
            int   pi0 = __shfl_xor(i0, d, 64);
            float pv1 = __shfl_xor(v1, d, 64);
            int   pi1 = __shfl_xor(i1, d, 64);
            top2_merge(v0, i0, v1, i1, pv0, pi0, pv1, pi1);
        }
        if (sub == 0) {
            float e1  = expf(v1 - v0);
            float inv = 1.0f / (1.0f + e1);
            rowout[row] = make_float4(inv, e1 * inv,
                                      __int_as_float(i0), __int_as_float(i1));
            float* idx_out = out + (size_t)NROWS * NEXP;
            *(float2*)&idx_out[(size_t)(blockM + row) * 2] =
                make_float2((float)i0, (float)i1);
        }
    }
    __syncthreads();

    // coalesced [32][64] output tile write
#pragma unroll
    for (int it = 0; it < 2; ++it) {
        int f  = it * 256 + tid;       // float4 id 0..511
        int m  = f >> 4;
        int c4 = (f & 15) << 2;
        float4 ro = rowout[m];
        int i0 = __float_as_int(ro.z);
        int i1 = __float_as_int(ro.w);
        float4 o;
        float* op = (float*)&o;
#pragma unroll
        for (int j = 0; j < 4; ++j) {
            int col = c4 + j;
            op[j] = (col == i0) ? ro.x : (col == i1) ? ro.y : 0.0f;
        }
        *(float4*)&out[(size_t)(blockM + m) * NEXP + c4] = o;
    }
}

extern "C" void kernel_launch(void* const* d_in, const int* in_sizes, int n_in,
                              void* d_out, int out_size, void* d_ws, size_t ws_size,
                              hipStream_t stream) {
    const float* x   = (const float*)d_in[0];
    const float* wr  = (const float*)d_in[1];
    const float* wn  = (const float*)d_in[2];
    const float* eps = (const float*)d_in[3];
    float* out = (float*)d_out;
    short* wp  = (short*)d_ws;   // 32 chunks * 12288 shorts = 1.5 MB scratch

    prep_w_kernel<<<dim3(512), dim3(256), 0, stream>>>(wr, wn, wp);
    router_kernel<<<dim3(NROWS / BM), dim3(256), 0, stream>>>(x, wp, eps, out);
}